// Round 1
// baseline (1365.708 us; speedup 1.0000x reference)
//
#include <hip/hip_runtime.h>
#include <math.h>

namespace {
constexpr int BB   = 8;
constexpr int CH   = 128;
constexpr int KC   = 64;
constexpr int HWD  = 256 * 256;        // 65536 pixels per batch
constexpr int TILE = 64;               // pixels per tile
constexpr int TPB  = 256;
constexpr int TILES_PER_B = HWD / TILE;  // 1024
constexpr int GB   = 64;               // k1 blocks per batch (each does 16 tiles)

// workspace layout (float offsets)
constexpr int OFF_SUMS  = 0;                       // [8][64][128] per-class xw sums
constexpr int OFF_CNT   = OFF_SUMS + BB*KC*CH;     // [8][64] class counts
constexpr int OFF_CHSQ  = OFF_CNT + BB*KC;         // [128] per-channel sum(xw^2)
constexpr int OFF_AM    = OFF_CHSQ + CH;           // [8][64][128] adj_means
constexpr int OFF_SCALE = OFF_AM + BB*KC*CH;       // [128]
constexpr int OFF_BIAS  = OFF_SCALE + CH;          // [128]
}

// ---------------------------------------------------------------------------
// K1: xw = x @ weight per pixel tile; accumulate per-(b,class) sums, counts,
//     and per-channel sum(xw^2). xw itself is NOT stored (recomputed in K4).
// ---------------------------------------------------------------------------
__global__ __launch_bounds__(TPB) void k1_xw_stats(
    const float* __restrict__ x, const int* __restrict__ index,
    const float* __restrict__ weight, float* __restrict__ ws)
{
  __shared__ float xs[CH][TILE];      // 32 KB x tile [channel][pixel]
  __shared__ float csum[KC][CH + 1];  // 33 KB padded class sums (pad kills bank conflicts)
  __shared__ float ccnt[KC];
  __shared__ float chsq_s[CH];

  const int t  = threadIdx.x;
  const int b  = blockIdx.x / GB;
  const int bb = blockIdx.x % GB;

  for (int i = t; i < KC * (CH + 1); i += TPB) (&csum[0][0])[i] = 0.f;
  if (t < KC) ccnt[t] = 0.f;
  if (t < CH) chsq_s[t] = 0.f;
  __syncthreads();

  const int p0 = (t & 15) * 4;   // 4 consecutive pixels
  const int d0 = (t >> 4) * 8;   // 8 consecutive output channels

  float sq[8];
#pragma unroll
  for (int i = 0; i < 8; ++i) sq[i] = 0.f;

  const float* xb = x + (size_t)b * CH * HWD;
  const int*   ib = index + (size_t)b * HWD;

  for (int tile = bb; tile < TILES_PER_B; tile += GB) {
    const int pix0 = tile * TILE;
    for (int i = t; i < CH * (TILE / 4); i += TPB) {
      const int c = i >> 4;
      const int p = (i & 15) << 2;
      *(float4*)&xs[c][p] = *(const float4*)&xb[(size_t)c * HWD + pix0 + p];
    }
    __syncthreads();

    const int4 kidx = *(const int4*)&ib[pix0 + p0];

    float acc[8][4];
#pragma unroll
    for (int i = 0; i < 8; ++i)
#pragma unroll
      for (int j = 0; j < 4; ++j) acc[i][j] = 0.f;

    const float* wrow = weight + d0;
#pragma unroll 4
    for (int c = 0; c < CH; ++c) {
      const float4 xv = *(const float4*)&xs[c][p0];
      const float4 wa = *(const float4*)&wrow[0];
      const float4 wb = *(const float4*)&wrow[4];
      wrow += CH;
      const float xj[4] = {xv.x, xv.y, xv.z, xv.w};
      const float wi[8] = {wa.x, wa.y, wa.z, wa.w, wb.x, wb.y, wb.z, wb.w};
#pragma unroll
      for (int i = 0; i < 8; ++i)
#pragma unroll
        for (int j = 0; j < 4; ++j) acc[i][j] += wi[i] * xj[j];
    }

    const int kk[4] = {kidx.x, kidx.y, kidx.z, kidx.w};
#pragma unroll
    for (int j = 0; j < 4; ++j) {
      float* crow = &csum[kk[j]][d0];
#pragma unroll
      for (int i = 0; i < 8; ++i) {
        const float v = acc[i][j];
        atomicAdd(&crow[i], v);
        sq[i] += v * v;
      }
    }
    if (t < 16) {
#pragma unroll
      for (int j = 0; j < 4; ++j) atomicAdd(&ccnt[kk[j]], 1.f);
    }
    __syncthreads();
  }

  // flush block-local accumulators to global (atomic across blocks)
  float* sums_g = ws + OFF_SUMS + (size_t)b * KC * CH;
  for (int i = t; i < KC * CH; i += TPB) {
    const int k = i >> 7, d = i & 127;
    atomicAdd(&sums_g[i], csum[k][d]);
  }
#pragma unroll
  for (int i = 0; i < 8; ++i) atomicAdd(&chsq_s[d0 + i], sq[i]);
  __syncthreads();
  if (t < KC) atomicAdd(&ws[OFF_CNT + b * KC + t], ccnt[t]);
  if (t < CH) atomicAdd(&ws[OFF_CHSQ + t], chsq_s[t]);
}

// ---------------------------------------------------------------------------
// K2: per-batch: means, Y = means@W, quad via |Y_q - Y_p|^2, adjacency,
//     adj_means = adj_nd @ means. One block per batch.
// ---------------------------------------------------------------------------
__global__ __launch_bounds__(TPB) void k2_adj(
    const float* __restrict__ Wm, const float* __restrict__ adj_mask,
    float* __restrict__ ws)
{
  __shared__ float ms[KC][CH + 1];
  __shared__ float Ys[KC][CH + 1];
  __shared__ float wm[KC][KC];
  __shared__ float yy[KC];
  const int b = blockIdx.x, t = threadIdx.x;
  const float* sums = ws + OFF_SUMS + (size_t)b * KC * CH;
  const float* cnt  = ws + OFF_CNT + b * KC;

  for (int i = t; i < KC * CH; i += TPB) {
    const int k = i >> 7, d = i & 127;
    const float c = cnt[k];
    ms[k][d] = sums[i] / (c == 0.f ? 1.f : c);
  }
  __syncthreads();

  // Y[k][e] = sum_c means[k][c] * W[c][e]   (quad = |W^T D|^2 factorization)
  for (int i = t; i < KC * CH; i += TPB) {
    const int k = i >> 7, e = i & 127;
    float a = 0.f;
    for (int c = 0; c < CH; ++c) a += ms[k][c] * Wm[c * CH + e];
    Ys[k][e] = a;
  }
  __syncthreads();

  if (t < KC) {
    float a = 0.f;
    for (int e = 0; e < CH; ++e) { const float v = Ys[t][e]; a += v * v; }
    yy[t] = a;
  }
  __syncthreads();

  // wm[p][q] = (p==q ? 0 : exp(-quad)*mask)  — diagonal is zeroed by (1-eye)
  for (int i = t; i < KC * KC; i += TPB) {
    const int p = i >> 6, q = i & 63;
    float g = 0.f;
    for (int e = 0; e < CH; ++e) g += Ys[p][e] * Ys[q][e];
    const float quad = yy[p] + yy[q] - 2.f * g;
    wm[p][q] = (p == q) ? 0.f : expf(-quad) * adj_mask[i];
  }
  __syncthreads();

  float* am = ws + OFF_AM + (size_t)b * KC * CH;
  for (int i = t; i < KC * CH; i += TPB) {
    const int p = i >> 7, d = i & 127;
    float a = 0.f;
    for (int q = 0; q < KC; ++q) a += wm[p][q] * ms[q][d];
    am[i] = a;
  }
}

// ---------------------------------------------------------------------------
// K3: BN statistics analytically from {sums, counts, chsq, adj_means}:
//   sum(f)  = sum(xw) + sum_bk cnt*am
//   sum(f²) = sum(xw²) + 2*sum_bk am*sums + sum_bk cnt*am²
// ---------------------------------------------------------------------------
__global__ __launch_bounds__(CH) void k3_bn(
    const float* __restrict__ gamma, const float* __restrict__ beta,
    float* __restrict__ ws)
{
  const int d = threadIdx.x;
  float chs = 0.f, cm = 0.f, cam2 = 0.f, cross = 0.f;
  for (int bk = 0; bk < BB * KC; ++bk) {
    const float c = ws[OFF_CNT + bk];
    const float a = ws[OFF_AM + (size_t)bk * CH + d];
    const float s = ws[OFF_SUMS + (size_t)bk * CH + d];
    chs += s; cm += c * a; cam2 += c * a * a; cross += a * s;
  }
  const float N   = (float)BB * (float)HWD;
  const float mu  = (chs + cm) / N;
  const float e2  = (ws[OFF_CHSQ + d] + 2.f * cross + cam2) / N;
  const float var = e2 - mu * mu;
  const float sc  = gamma[d] / sqrtf(var + 1e-5f);
  ws[OFF_SCALE + d] = sc;
  ws[OFF_BIAS + d]  = beta[d] - mu * sc;
}

// ---------------------------------------------------------------------------
// K4: recompute xw, add gathered adj_means, apply BN affine, write out.
// ---------------------------------------------------------------------------
__global__ __launch_bounds__(TPB) void k4_out(
    const float* __restrict__ x, const int* __restrict__ index,
    const float* __restrict__ weight, const float* __restrict__ ws,
    float* __restrict__ out)
{
  __shared__ float xs[CH][TILE];
  const int t    = threadIdx.x;
  const int b    = blockIdx.x / TILES_PER_B;
  const int tile = blockIdx.x % TILES_PER_B;
  const int pix0 = tile * TILE;
  const float* xb = x + (size_t)b * CH * HWD;

  for (int i = t; i < CH * (TILE / 4); i += TPB) {
    const int c = i >> 4;
    const int p = (i & 15) << 2;
    *(float4*)&xs[c][p] = *(const float4*)&xb[(size_t)c * HWD + pix0 + p];
  }
  __syncthreads();

  const int p0 = (t & 15) * 4;
  const int d0 = (t >> 4) * 8;
  const int4 kidx = *(const int4*)&index[(size_t)b * HWD + pix0 + p0];

  float acc[8][4];
#pragma unroll
  for (int i = 0; i < 8; ++i)
#pragma unroll
    for (int j = 0; j < 4; ++j) acc[i][j] = 0.f;

  const float* wrow = weight + d0;
#pragma unroll 4
  for (int c = 0; c < CH; ++c) {
    const float4 xv = *(const float4*)&xs[c][p0];
    const float4 wa = *(const float4*)&wrow[0];
    const float4 wb = *(const float4*)&wrow[4];
    wrow += CH;
    const float xj[4] = {xv.x, xv.y, xv.z, xv.w};
    const float wi[8] = {wa.x, wa.y, wa.z, wa.w, wb.x, wb.y, wb.z, wb.w};
#pragma unroll
    for (int i = 0; i < 8; ++i)
#pragma unroll
      for (int j = 0; j < 4; ++j) acc[i][j] += wi[i] * xj[j];
  }

  const float* am = ws + OFF_AM + (size_t)b * KC * CH;
  const int kk[4] = {kidx.x, kidx.y, kidx.z, kidx.w};
  float amv[4][8];
#pragma unroll
  for (int j = 0; j < 4; ++j) {
    const float4 a0 = *(const float4*)&am[(size_t)kk[j] * CH + d0];
    const float4 a1 = *(const float4*)&am[(size_t)kk[j] * CH + d0 + 4];
    amv[j][0] = a0.x; amv[j][1] = a0.y; amv[j][2] = a0.z; amv[j][3] = a0.w;
    amv[j][4] = a1.x; amv[j][5] = a1.y; amv[j][6] = a1.z; amv[j][7] = a1.w;
  }

  const float4 s0 = *(const float4*)&ws[OFF_SCALE + d0];
  const float4 s1 = *(const float4*)&ws[OFF_SCALE + d0 + 4];
  const float4 b0 = *(const float4*)&ws[OFF_BIAS + d0];
  const float4 b1 = *(const float4*)&ws[OFF_BIAS + d0 + 4];
  const float sc[8] = {s0.x, s0.y, s0.z, s0.w, s1.x, s1.y, s1.z, s1.w};
  const float bi[8] = {b0.x, b0.y, b0.z, b0.w, b1.x, b1.y, b1.z, b1.w};

#pragma unroll
  for (int i = 0; i < 8; ++i) {
    float4 o;
    o.x = (acc[i][0] + amv[0][i]) * sc[i] + bi[i];
    o.y = (acc[i][1] + amv[1][i]) * sc[i] + bi[i];
    o.z = (acc[i][2] + amv[2][i]) * sc[i] + bi[i];
    o.w = (acc[i][3] + amv[3][i]) * sc[i] + bi[i];
    *(float4*)&out[((size_t)b * CH + d0 + i) * HWD + pix0 + p0] = o;
  }
}

extern "C" void kernel_launch(void* const* d_in, const int* in_sizes, int n_in,
                              void* d_out, int out_size, void* d_ws, size_t ws_size,
                              hipStream_t stream) {
  const float* x        = (const float*)d_in[0];
  const int*   index    = (const int*)d_in[1];
  const float* weight   = (const float*)d_in[2];
  const float* Wm       = (const float*)d_in[3];
  const float* adj_mask = (const float*)d_in[4];
  const float* gamma    = (const float*)d_in[5];
  const float* beta     = (const float*)d_in[6];
  float* ws  = (float*)d_ws;
  float* out = (float*)d_out;

  // zero the atomic accumulators (sums, counts, chsq) — ws is poisoned each call
  hipMemsetAsync(ws, 0, (size_t)OFF_AM * sizeof(float), stream);

  k1_xw_stats<<<BB * GB, TPB, 0, stream>>>(x, index, weight, ws);
  k2_adj<<<BB, TPB, 0, stream>>>(Wm, adj_mask, ws);
  k3_bn<<<1, CH, 0, stream>>>(gamma, beta, ws);
  k4_out<<<BB * TILES_PER_B, TPB, 0, stream>>>(x, index, weight, ws, out);
}

// Round 2
// 970.367 us; speedup vs baseline: 1.4074x; 1.4074x over previous
//
#include <hip/hip_runtime.h>
#include <math.h>

typedef __attribute__((ext_vector_type(8))) short bf16x8;
typedef __attribute__((ext_vector_type(4))) float f32x4;

namespace {
constexpr int BB = 8, CH = 128, KC = 64, HWD = 65536;
constexpr int TILE = 64;                 // px per tile
constexpr int TPB  = 256;                // 4 waves
constexpr int TILES_PER_BLOCK = 16;      // 1024 px per block
constexpr int PX_PER_BLOCK = TILE * TILES_PER_BLOCK;
constexpr int BLOCKS_PER_B = HWD / PX_PER_BLOCK;   // 64
constexpr int XS_STRIDE = 136;           // bf16 row stride (+8 pad, keeps 16B align)

// workspace float offsets
constexpr int OFF_SUMS  = 0;                     // [8][64][128]
constexpr int OFF_CNT   = OFF_SUMS + BB*KC*CH;   // [8][64]
constexpr int OFF_CHSQ  = OFF_CNT + BB*KC;       // [128]
constexpr int OFF_AM    = OFF_CHSQ + CH;         // [8][64][128]
constexpr int OFF_SCALE = OFF_AM + BB*KC*CH;     // [128]
constexpr int OFF_BIAS  = OFF_SCALE + CH;        // [128]
constexpr int OFF_AMSB  = OFF_BIAS + CH;         // [8][64][128] am*sc+bi
}

__device__ __forceinline__ short f2bf(float f) {   // RNE fp32->bf16
  unsigned u = __builtin_bit_cast(unsigned, f);
  u += 0x7fffu + ((u >> 16) & 1u);
  return (short)(u >> 16);
}

// A-operand (weight^T) fragments held in registers for the whole kernel.
// A[m=d][k=c]: lane m = lane&15 (d), k = quad*8+j (c). 4 M-tiles x 4 K-chunks.
__device__ __forceinline__ void load_w_frags(const float* __restrict__ w,
                                             int mbase, int lane15, int quad,
                                             bf16x8 af[4][4]) {
#pragma unroll
  for (int mt = 0; mt < 4; ++mt) {
    const int d = mbase + mt * 16 + lane15;
#pragma unroll
    for (int kc = 0; kc < 4; ++kc) {
      const int c0 = kc * 32 + quad * 8;
      bf16x8 f;
#pragma unroll
      for (int j = 0; j < 8; ++j) f[j] = f2bf(w[(size_t)(c0 + j) * CH + d]);
      af[mt][kc] = f;
    }
  }
}

// Stage 64 px x 128 c of x (fp32 [c][p]) into LDS as bf16 [p][c] (transposed).
// Thread t: px p0..p0+3, channels c0..c0+7. Global: 8x float4 (256B segments).
// LDS: 4x ds_write_b128; start banks 4*((t&15)+(t>>4))%32 -> conflict-optimal.
__device__ __forceinline__ void stage_x(const float* __restrict__ xb, int pix0,
                                        short* __restrict__ xs, int t) {
  const int p0 = (t & 15) * 4, c0 = (t >> 4) * 8;
  float4 v[8];
#pragma unroll
  for (int j = 0; j < 8; ++j)
    v[j] = *(const float4*)&xb[(size_t)(c0 + j) * HWD + pix0 + p0];
#pragma unroll
  for (int pp = 0; pp < 4; ++pp) {
    bf16x8 f;
#pragma unroll
    for (int j = 0; j < 8; ++j) f[j] = f2bf(((const float*)&v[j])[pp]);
    *(bf16x8*)&xs[(p0 + pp) * XS_STRIDE + c0] = f;
  }
}

// ---------------------------------------------------------------------------
// K1: MFMA xw tile; accumulate per-(b,class) sums (LDS atomics, +1 pad),
// counts, per-lane fp32 sum(xw^2). xw NOT stored (recomputed bitwise in K4).
// ---------------------------------------------------------------------------
__global__ __launch_bounds__(TPB) void k1_mfma(
    const float* __restrict__ x, const int* __restrict__ index,
    const float* __restrict__ weight, float* __restrict__ ws)
{
  __shared__ short xs[TILE * XS_STRIDE];       // 17 KB
  __shared__ float csum[KC][CH + 1];           // 33 KB, bank=(cls+d)%32
  __shared__ float ccnt[KC];
  __shared__ float chsq_s[CH];

  const int t = threadIdx.x;
  const int lane = t & 63, lane15 = lane & 15, quad = lane >> 4, w = t >> 6;
  const int mbase = (w & 1) * 64;              // d-half owned by this wave
  const int nbase = (w >> 1) * 32;             // px-half owned by this wave
  const int b = blockIdx.x / BLOCKS_PER_B;
  const int px_base = (blockIdx.x % BLOCKS_PER_B) * PX_PER_BLOCK;

  for (int i = t; i < KC * (CH + 1); i += TPB) (&csum[0][0])[i] = 0.f;
  if (t < KC) ccnt[t] = 0.f;
  if (t < CH) chsq_s[t] = 0.f;

  bf16x8 af[4][4];
  load_w_frags(weight, mbase, lane15, quad, af);

  float sq[4][4] = {};
  const float* xb = x + (size_t)b * CH * HWD;
  const int*   ib = index + (size_t)b * HWD;
  __syncthreads();

  for (int tile = 0; tile < TILES_PER_BLOCK; ++tile) {
    const int pix0 = px_base + tile * TILE;
    stage_x(xb, pix0, xs, t);
    __syncthreads();

    int cls[2];
#pragma unroll
    for (int nt = 0; nt < 2; ++nt) cls[nt] = ib[pix0 + nbase + nt * 16 + lane15];

    f32x4 acc[4][2] = {};
#pragma unroll
    for (int kc = 0; kc < 4; ++kc) {
      bf16x8 bfr[2];
#pragma unroll
      for (int nt = 0; nt < 2; ++nt)
        bfr[nt] = *(const bf16x8*)&xs[(nbase + nt * 16 + lane15) * XS_STRIDE + kc * 32 + quad * 8];
#pragma unroll
      for (int mt = 0; mt < 4; ++mt)
#pragma unroll
        for (int nt = 0; nt < 2; ++nt)
          acc[mt][nt] = __builtin_amdgcn_mfma_f32_16x16x32_bf16(af[mt][kc], bfr[nt], acc[mt][nt], 0, 0, 0);
    }

    // D layout: lane px = lane&15 (+tile base), d = mbase+mt*16+quad*4+r
#pragma unroll
    for (int nt = 0; nt < 2; ++nt) {
      float* cr = &csum[cls[nt]][0];
#pragma unroll
      for (int mt = 0; mt < 4; ++mt)
#pragma unroll
        for (int r = 0; r < 4; ++r) {
          const float v = acc[mt][nt][r];
          atomicAdd(&cr[mbase + mt * 16 + quad * 4 + r], v);
          sq[mt][r] += v * v;
        }
    }
    if ((w & 1) == 0 && lane < 16) {   // one wave per px-half, quad 0 only
      atomicAdd(&ccnt[cls[0]], 1.f);
      atomicAdd(&ccnt[cls[1]], 1.f);
    }
    __syncthreads();
  }

  // flush block-local accumulators
  float* sums_g = ws + OFF_SUMS + (size_t)b * KC * CH;
  for (int i = t; i < KC * CH; i += TPB)
    atomicAdd(&sums_g[i], csum[i >> 7][i & 127]);
#pragma unroll
  for (int mt = 0; mt < 4; ++mt)
#pragma unroll
    for (int r = 0; r < 4; ++r)
      atomicAdd(&chsq_s[mbase + mt * 16 + quad * 4 + r], sq[mt][r]);
  __syncthreads();
  if (t < KC) atomicAdd(&ws[OFF_CNT + b * KC + t], ccnt[t]);
  if (t < CH) atomicAdd(&ws[OFF_CHSQ + t], chsq_s[t]);
}

// ---------------------------------------------------------------------------
// K2: per-batch means, Y = means@W, quad = |Y_p - Y_q|^2, adjacency,
// adj_means = adj_nd @ means. One block per batch. (unchanged, ~µs)
// ---------------------------------------------------------------------------
__global__ __launch_bounds__(TPB) void k2_adj(
    const float* __restrict__ Wm, const float* __restrict__ adj_mask,
    float* __restrict__ ws)
{
  __shared__ float ms[KC][CH + 1];
  __shared__ float Ys[KC][CH + 1];
  __shared__ float wm[KC][KC];
  __shared__ float yy[KC];
  const int b = blockIdx.x, t = threadIdx.x;
  const float* sums = ws + OFF_SUMS + (size_t)b * KC * CH;
  const float* cnt  = ws + OFF_CNT + b * KC;

  for (int i = t; i < KC * CH; i += TPB) {
    const int k = i >> 7, d = i & 127;
    const float c = cnt[k];
    ms[k][d] = sums[i] / (c == 0.f ? 1.f : c);
  }
  __syncthreads();
  for (int i = t; i < KC * CH; i += TPB) {
    const int k = i >> 7, e = i & 127;
    float a = 0.f;
    for (int c = 0; c < CH; ++c) a += ms[k][c] * Wm[c * CH + e];
    Ys[k][e] = a;
  }
  __syncthreads();
  if (t < KC) {
    float a = 0.f;
    for (int e = 0; e < CH; ++e) { const float v = Ys[t][e]; a += v * v; }
    yy[t] = a;
  }
  __syncthreads();
  for (int i = t; i < KC * KC; i += TPB) {
    const int p = i >> 6, q = i & 63;
    float g = 0.f;
    for (int e = 0; e < CH; ++e) g += Ys[p][e] * Ys[q][e];
    const float quad = yy[p] + yy[q] - 2.f * g;
    wm[p][q] = (p == q) ? 0.f : expf(-quad) * adj_mask[i];
  }
  __syncthreads();
  float* am = ws + OFF_AM + (size_t)b * KC * CH;
  for (int i = t; i < KC * CH; i += TPB) {
    const int p = i >> 7, d = i & 127;
    float a = 0.f;
    for (int q = 0; q < KC; ++q) a += wm[p][q] * ms[q][d];
    am[i] = a;
  }
}

// ---------------------------------------------------------------------------
// K3: analytic BN stats + fused amSB = am*sc + bi. 64 blocks x 128 threads;
// each block redoes the tiny 512-iter stat loop (L2-hot), writes 8 amSB rows.
// ---------------------------------------------------------------------------
__global__ __launch_bounds__(CH) void k3_bn(
    const float* __restrict__ gamma, const float* __restrict__ beta,
    float* __restrict__ ws)
{
  const int d = threadIdx.x;
  float chs = 0.f, cm = 0.f, cam2 = 0.f, cross = 0.f;
  for (int bk = 0; bk < BB * KC; ++bk) {
    const float c = ws[OFF_CNT + bk];
    const float a = ws[OFF_AM + (size_t)bk * CH + d];
    const float s = ws[OFF_SUMS + (size_t)bk * CH + d];
    chs += s; cm += c * a; cam2 += c * a * a; cross += a * s;
  }
  const float N   = (float)BB * (float)HWD;
  const float mu  = (chs + cm) / N;
  const float e2  = (ws[OFF_CHSQ + d] + 2.f * cross + cam2) / N;
  const float var = e2 - mu * mu;
  const float sc  = gamma[d] / sqrtf(var + 1e-5f);
  const float bi  = beta[d] - mu * sc;
  if (blockIdx.x == 0) { ws[OFF_SCALE + d] = sc; ws[OFF_BIAS + d] = bi; }
  for (int r = 0; r < 8; ++r) {
    const int bk = blockIdx.x * 8 + r;
    ws[OFF_AMSB + (size_t)bk * CH + d] = ws[OFF_AM + (size_t)bk * CH + d] * sc + bi;
  }
}

// ---------------------------------------------------------------------------
// K4: recompute xw (bitwise-identical MFMA), out = xw*sc + amSB[cls][d].
// Stores: lanes 0-15 contiguous px at fixed d -> 64B segments.
// ---------------------------------------------------------------------------
__global__ __launch_bounds__(TPB) void k4_mfma(
    const float* __restrict__ x, const int* __restrict__ index,
    const float* __restrict__ weight, const float* __restrict__ ws,
    float* __restrict__ out)
{
  __shared__ short xs[TILE * XS_STRIDE];       // 17 KB
  __shared__ float amsb[KC][CH + 4];           // 33 KB, stride 132 (16B-aligned)

  const int t = threadIdx.x;
  const int lane = t & 63, lane15 = lane & 15, quad = lane >> 4, w = t >> 6;
  const int mbase = (w & 1) * 64;
  const int nbase = (w >> 1) * 32;
  const int b = blockIdx.x / BLOCKS_PER_B;
  const int px_base = (blockIdx.x % BLOCKS_PER_B) * PX_PER_BLOCK;

  const float* ag = ws + OFF_AMSB + (size_t)b * KC * CH;
  for (int i = t; i < KC * CH / 4; i += TPB) {
    const int k = (i * 4) >> 7, dd = (i * 4) & 127;
    *(float4*)&amsb[k][dd] = *(const float4*)&ag[k * CH + dd];
  }

  bf16x8 af[4][4];
  load_w_frags(weight, mbase, lane15, quad, af);

  float scr[4][4];
#pragma unroll
  for (int mt = 0; mt < 4; ++mt)
#pragma unroll
    for (int r = 0; r < 4; ++r)
      scr[mt][r] = ws[OFF_SCALE + mbase + mt * 16 + quad * 4 + r];

  const float* xb = x + (size_t)b * CH * HWD;
  const int*   ib = index + (size_t)b * HWD;
  float*       ob = out + (size_t)b * CH * HWD;
  __syncthreads();

  for (int tile = 0; tile < TILES_PER_BLOCK; ++tile) {
    const int pix0 = px_base + tile * TILE;
    stage_x(xb, pix0, xs, t);
    __syncthreads();

    int cls[2];
#pragma unroll
    for (int nt = 0; nt < 2; ++nt) cls[nt] = ib[pix0 + nbase + nt * 16 + lane15];

    f32x4 acc[4][2] = {};
#pragma unroll
    for (int kc = 0; kc < 4; ++kc) {
      bf16x8 bfr[2];
#pragma unroll
      for (int nt = 0; nt < 2; ++nt)
        bfr[nt] = *(const bf16x8*)&xs[(nbase + nt * 16 + lane15) * XS_STRIDE + kc * 32 + quad * 8];
#pragma unroll
      for (int mt = 0; mt < 4; ++mt)
#pragma unroll
        for (int nt = 0; nt < 2; ++nt)
          acc[mt][nt] = __builtin_amdgcn_mfma_f32_16x16x32_bf16(af[mt][kc], bfr[nt], acc[mt][nt], 0, 0, 0);
    }

#pragma unroll
    for (int nt = 0; nt < 2; ++nt) {
      const float* ar = &amsb[cls[nt]][0];
      const int px = pix0 + nbase + nt * 16 + lane15;
#pragma unroll
      for (int mt = 0; mt < 4; ++mt)
#pragma unroll
        for (int r = 0; r < 4; ++r) {
          const int d = mbase + mt * 16 + quad * 4 + r;
          ob[(size_t)d * HWD + px] = acc[mt][nt][r] * scr[mt][r] + ar[d];
        }
    }
    __syncthreads();
  }
}

extern "C" void kernel_launch(void* const* d_in, const int* in_sizes, int n_in,
                              void* d_out, int out_size, void* d_ws, size_t ws_size,
                              hipStream_t stream) {
  const float* x        = (const float*)d_in[0];
  const int*   index    = (const int*)d_in[1];
  const float* weight   = (const float*)d_in[2];
  const float* Wm       = (const float*)d_in[3];
  const float* adj_mask = (const float*)d_in[4];
  const float* gamma    = (const float*)d_in[5];
  const float* beta     = (const float*)d_in[6];
  float* ws  = (float*)d_ws;
  float* out = (float*)d_out;

  // zero the cross-block atomic accumulators (sums, counts, chsq)
  hipMemsetAsync(ws, 0, (size_t)OFF_AM * sizeof(float), stream);

  k1_mfma<<<BB * BLOCKS_PER_B, TPB, 0, stream>>>(x, index, weight, ws);
  k2_adj <<<BB, TPB, 0, stream>>>(Wm, adj_mask, ws);
  k3_bn  <<<KC, CH, 0, stream>>>(gamma, beta, ws);
  k4_mfma<<<BB * BLOCKS_PER_B, TPB, 0, stream>>>(x, index, weight, ws, out);
}